// Round 4
// baseline (422.950 us; speedup 1.0000x reference)
//
#include <hip/hip_runtime.h>
#include <hip/hip_bf16.h>

// out[i] = sum_{j!=i} relu(Wd_i@x_j + (Ws_i-Wd_i)@x_i + b_i) * x_j + x_i, 3 steps.
// MFMA 16x16x32 bf16, 3-way split (hi/mid/lo) of W and x -> fp32-equivalent
// (absmax 0.5 vs threshold 39.5; 2-way split projects to ~127 -> must keep 3).
// LDS: 3 bf16 split copies (B-frags) + fp32 gating copy xg. Resident awd+awsd.
// Sender MFMA chain split into 2 independent 3-deep chains (latency hiding).
// Epilogue staged through LDS -> full-line coalesced f32x4 stores (round-3's
// direct stores caused 2.3x write amplification).

#define NN 8
#define NSTEPS 3
#define BB 4
#define CC 32
#define HWSZ 9216
#define PX 16
#define CPS 40   // bf16 row stride (80 B, 16B-aligned)
#define CPG 36   // f32 row stride (144 B, 16B-aligned)

typedef __bf16 bf16x8 __attribute__((ext_vector_type(8)));
typedef __bf16 bf16x4 __attribute__((ext_vector_type(4)));
typedef __bf16 bf16x2 __attribute__((ext_vector_type(2)));
typedef float  f32x4  __attribute__((ext_vector_type(4)));
typedef float  f32x2  __attribute__((ext_vector_type(2)));

#define MFMA(A, B, C) __builtin_amdgcn_mfma_f32_16x16x32_bf16((A), (B), (C), 0, 0, 0)

__device__ __forceinline__ void split3(float v, __bf16& h, __bf16& m, __bf16& l) {
    h = (__bf16)v;
    float r1 = v - (float)h;
    m = (__bf16)r1;
    l = (__bf16)(r1 - (float)m);
}

__global__ __launch_bounds__(256, 3)
void gcn3_mfma3(const float* __restrict__ nodes,
                const float* __restrict__ we,
                const float* __restrict__ be,
                float* __restrict__ out) {
    __shared__ __bf16 xs[3][NN][PX][CPS];   // 30720 B
    __shared__ float  xg[NN][PX][CPG];      // 18432 B  (total 49152)

    const int tid  = threadIdx.x;
    const int wid  = tid >> 6;
    const int lane = tid & 63;
    const int col  = lane & 15;    // pixel (B-frag n / C col); A-frag row m
    const int quad = lane >> 4;    // 0..3

    // ---- resident A-frags: Wd and (Ws-Wd), 3-way split ----
    bf16x8 awd[2][2][3], awsd[2][2][3];   // [rec][tile][split]
    f32x4  bias[2][2];
    #pragma unroll
    for (int r = 0; r < 2; ++r) {
        const int ir = wid + 4 * r;
        #pragma unroll
        for (int t = 0; t < 2; ++t) {
            const float* wp = we + (size_t)((ir * CC + 16 * t + col) * (2 * CC)) + quad * 8;
            f32x4 d0 = *(const f32x4*)wp;
            f32x4 d1 = *(const f32x4*)(wp + 4);
            f32x4 s0 = *(const f32x4*)(wp + CC);
            f32x4 s1 = *(const f32x4*)(wp + CC + 4);
            #pragma unroll
            for (int k = 0; k < 8; ++k) {
                float d = (k < 4) ? d0[k & 3] : d1[k & 3];
                float s = (k < 4) ? s0[k & 3] : s1[k & 3];
                __bf16 h, m, l;
                split3(d, h, m, l);
                awd[r][t][0][k] = h; awd[r][t][1][k] = m; awd[r][t][2][k] = l;
                split3(s - d, h, m, l);
                awsd[r][t][0][k] = h; awsd[r][t][1][k] = m; awsd[r][t][2][k] = l;
            }
            #pragma unroll
            for (int k = 0; k < 4; ++k)
                bias[r][t][k] = be[ir * CC + 16 * t + quad * 4 + k];
        }
    }

    const int q0  = blockIdx.x * PX;
    const int b   = q0 / HWSZ;
    const int hw0 = q0 - b * HWSZ;

    // ---- stage: 2 channels x 2 pixels per thread ----
    #pragma unroll
    for (int kk = 0; kk < 4; ++kk) {
        int idx = tid + kk * 256;            // 1024 = 8n * 16c2 * 8p2
        int p2 = (idx & 7) * 2;
        int c2 = ((idx >> 3) & 15) * 2;
        int n  = idx >> 7;
        const float* gp = nodes + (size_t)((n * BB + b) * CC + c2) * HWSZ + hw0 + p2;
        f32x2 v0 = *(const f32x2*)gp;            // channel c2
        f32x2 v1 = *(const f32x2*)(gp + HWSZ);   // channel c2+1
        #pragma unroll
        for (int e = 0; e < 2; ++e) {
            __bf16 h0, m0, l0, h1, m1, l1;
            split3(v0[e], h0, m0, l0);
            split3(v1[e], h1, m1, l1);
            *(bf16x2*)&xs[0][n][p2 + e][c2] = bf16x2{h0, h1};
            *(bf16x2*)&xs[1][n][p2 + e][c2] = bf16x2{m0, m1};
            *(bf16x2*)&xs[2][n][p2 + e][c2] = bf16x2{l0, l1};
            *(f32x2*)&xg[n][p2 + e][c2] = f32x2{v0[e], v1[e]};
        }
    }
    __syncthreads();

    f32x4 msg[2][2];

    #pragma unroll 1
    for (int step = 0; step < NSTEPS; ++step) {
        // ---- Q = (Ws-Wd)_i @ x_i + b, two 3-deep chains ----
        f32x4 qf[2][2];
        #pragma unroll
        for (int r = 0; r < 2; ++r) {
            const int ir = wid + 4 * r;
            bf16x8 bq0 = *(const bf16x8*)&xs[0][ir][col][quad * 8];
            bf16x8 bq1 = *(const bf16x8*)&xs[1][ir][col][quad * 8];
            bf16x8 bq2 = *(const bf16x8*)&xs[2][ir][col][quad * 8];
            #pragma unroll
            for (int t = 0; t < 2; ++t) {
                f32x4 qa = bias[r][t];
                qa = MFMA(awsd[r][t][0], bq0, qa);   // hh
                qa = MFMA(awsd[r][t][0], bq1, qa);   // hm
                qa = MFMA(awsd[r][t][1], bq0, qa);   // mh
                f32x4 qb = {0.f, 0.f, 0.f, 0.f};
                qb = MFMA(awsd[r][t][0], bq2, qb);   // hl
                qb = MFMA(awsd[r][t][2], bq0, qb);   // lh
                qb = MFMA(awsd[r][t][1], bq1, qb);   // mm
                #pragma unroll
                for (int k = 0; k < 4; ++k) qf[r][t][k] = qa[k] + qb[k];
            }
        }

        #pragma unroll
        for (int r = 0; r < 2; ++r)
            #pragma unroll
            for (int t = 0; t < 2; ++t)
                msg[r][t] = f32x4{0.f, 0.f, 0.f, 0.f};

        // ---- sender loop ----
        #pragma unroll
        for (int j = 0; j < NN; ++j) {
            bf16x8 bj0 = *(const bf16x8*)&xs[0][j][col][quad * 8];
            bf16x8 bj1 = *(const bf16x8*)&xs[1][j][col][quad * 8];
            bf16x8 bj2 = *(const bf16x8*)&xs[2][j][col][quad * 8];
            f32x4 xgj[2];
            #pragma unroll
            for (int t = 0; t < 2; ++t)
                xgj[t] = *(const f32x4*)&xg[j][col][16 * t + quad * 4];
            #pragma unroll
            for (int r = 0; r < 2; ++r) {
                if (j == wid + 4 * r) {          // wave-uniform: residual, no MFMA
                    #pragma unroll
                    for (int t = 0; t < 2; ++t)
                        #pragma unroll
                        for (int k = 0; k < 4; ++k)
                            msg[r][t][k] += xgj[t][k];
                } else {
                    #pragma unroll
                    for (int t = 0; t < 2; ++t) {
                        f32x4 e1 = qf[r][t];
                        e1 = MFMA(awd[r][t][0], bj0, e1);   // hh
                        e1 = MFMA(awd[r][t][0], bj1, e1);   // hm
                        e1 = MFMA(awd[r][t][1], bj0, e1);   // mh
                        f32x4 e2 = {0.f, 0.f, 0.f, 0.f};
                        e2 = MFMA(awd[r][t][0], bj2, e2);   // hl
                        e2 = MFMA(awd[r][t][2], bj0, e2);   // lh
                        e2 = MFMA(awd[r][t][1], bj1, e2);   // mm
                        #pragma unroll
                        for (int k = 0; k < 4; ++k) {
                            float g = fmaxf(e1[k] + e2[k], 0.f);
                            msg[r][t][k] = fmaf(g, xgj[t][k], msg[r][t][k]);
                        }
                    }
                }
            }
        }

        if (step < NSTEPS - 1) {
            __syncthreads();   // all reads of old x done
            #pragma unroll
            for (int r = 0; r < 2; ++r) {
                const int ir = wid + 4 * r;
                #pragma unroll
                for (int t = 0; t < 2; ++t) {
                    bf16x4 h4, m4, l4;
                    #pragma unroll
                    for (int k = 0; k < 4; ++k) {
                        __bf16 h, m, l;
                        split3(msg[r][t][k], h, m, l);
                        h4[k] = h; m4[k] = m; l4[k] = l;
                    }
                    *(bf16x4*)&xs[0][ir][col][16 * t + quad * 4] = h4;
                    *(bf16x4*)&xs[1][ir][col][16 * t + quad * 4] = m4;
                    *(bf16x4*)&xs[2][ir][col][16 * t + quad * 4] = l4;
                    *(f32x4*)&xg[ir][col][16 * t + quad * 4] = msg[r][t];
                }
            }
            __syncthreads();   // new x visible
        }
    }

    // ---- epilogue: stage final msg in LDS, then full-line coalesced stores ----
    __syncthreads();
    #pragma unroll
    for (int r = 0; r < 2; ++r) {
        const int ir = wid + 4 * r;
        #pragma unroll
        for (int t = 0; t < 2; ++t)
            *(f32x4*)&xg[ir][col][16 * t + quad * 4] = msg[r][t];
    }
    __syncthreads();
    #pragma unroll
    for (int kk = 0; kk < 4; ++kk) {
        int idx = tid + kk * 256;            // 1024 = 8n * 32c * 4p4
        int p4 = (idx & 3) * 4;
        int c  = (idx >> 2) & 31;
        int n  = idx >> 7;
        f32x4 v;
        #pragma unroll
        for (int e = 0; e < 4; ++e) v[e] = xg[n][p4 + e][c];
        *(f32x4*)(out + (size_t)((n * BB + b) * CC + c) * HWSZ + hw0 + p4) = v;
    }
}

extern "C" void kernel_launch(void* const* d_in, const int* in_sizes, int n_in,
                              void* d_out, int out_size, void* d_ws, size_t ws_size,
                              hipStream_t stream) {
    const float* nodes  = (const float*)d_in[0];
    const float* W_edge = (const float*)d_in[1];
    const float* b_edge = (const float*)d_in[2];
    float* outp = (float*)d_out;

    dim3 grid((BB * HWSZ) / PX);   // 2304
    dim3 block(256);
    gcn3_mfma3<<<grid, block, 0, stream>>>(nodes, W_edge, b_edge, outp);
}

// Round 6
// 334.844 us; speedup vs baseline: 1.2631x; 1.2631x over previous
//
#include <hip/hip_runtime.h>
#include <hip/hip_bf16.h>

// out[i] = sum_{j!=i} relu(Wd_i@x_j + (Ws_i-Wd_i)@x_i + b_i) * x_j + x_i, 3 steps.
// MFMA 16x16x32 f16 with SCALED 2-WAY f16 split: v = h + m*2^-11,
//   h = f16(v), m = f16((v-h)*2048)  -> rep err ~2^-24 (fp32-class), m kept
//   in normal f16 range (no denormal flush risk).
// Edge products: keep hh, hm, mh (e = e1 + 2^-11*e2); drop mm (rel 2^-22).
// Q keeps all 4 terms. vs bf16 3-split: 3 MFMA/edge not 6, 2 LDS copies not 3,
// 64 weight VGPRs not 96 -> fits 3 waves/SIMD (~170 reg budget) w/o spills.
// LDS: f16 split pair xs[2] (B-frags) + fp32 gating master xg. Epilogue staged
// through LDS for full-line coalesced stores (R3 direct stores: 2.3x write amp).

#define NN 8
#define NSTEPS 3
#define BB 4
#define CC 32
#define HWSZ 9216
#define PX 16
#define CPS 40   // f16 row stride (80 B)
#define CPG 36   // f32 row stride (144 B)
#define MSC 2048.0f
#define SINV 4.8828125e-4f   // 2^-11

typedef _Float16 f16x8 __attribute__((ext_vector_type(8)));
typedef _Float16 f16x4 __attribute__((ext_vector_type(4)));
typedef _Float16 f16x2 __attribute__((ext_vector_type(2)));
typedef float    f32x4 __attribute__((ext_vector_type(4)));
typedef float    f32x2 __attribute__((ext_vector_type(2)));

#define MFMA(A, B, C) __builtin_amdgcn_mfma_f32_16x16x32_f16((A), (B), (C), 0, 0, 0)

__device__ __forceinline__ void split2s(float v, _Float16& h, _Float16& m) {
    h = (_Float16)v;
    m = (_Float16)((v - (float)h) * MSC);
}

__global__ __launch_bounds__(256, 3)
void gcn3_f16(const float* __restrict__ nodes,
              const float* __restrict__ we,
              const float* __restrict__ be,
              float* __restrict__ out) {
    __shared__ _Float16 xs[2][NN][PX][CPS];   // 20480 B
    __shared__ float    xg[NN][PX][CPG];      // 18432 B (total 38912)

    const int tid  = threadIdx.x;
    const int wid  = tid >> 6;
    const int lane = tid & 63;
    const int col  = lane & 15;    // pixel (B n / C col); A row m
    const int quad = lane >> 4;    // 0..3

    const f32x4 zero4 = {0.f, 0.f, 0.f, 0.f};

    // ---- resident A-frags: Wd and (Ws-Wd), scaled 2-way f16 split ----
    f16x8 awd[2][2][2], awsd[2][2][2];   // [rec][tile][split] = 64 VGPRs
    f32x4 bias[2][2];
    #pragma unroll
    for (int r = 0; r < 2; ++r) {
        const int ir = wid + 4 * r;
        #pragma unroll
        for (int t = 0; t < 2; ++t) {
            const float* wp = we + (size_t)((ir * CC + 16 * t + col) * (2 * CC)) + quad * 8;
            f32x4 d0 = *(const f32x4*)wp;
            f32x4 d1 = *(const f32x4*)(wp + 4);
            f32x4 s0 = *(const f32x4*)(wp + CC);
            f32x4 s1 = *(const f32x4*)(wp + CC + 4);
            #pragma unroll
            for (int k = 0; k < 8; ++k) {
                float d = (k < 4) ? d0[k & 3] : d1[k & 3];
                float s = (k < 4) ? s0[k & 3] : s1[k & 3];
                _Float16 h, m;
                split2s(d, h, m);
                awd[r][t][0][k] = h; awd[r][t][1][k] = m;
                split2s(s - d, h, m);
                awsd[r][t][0][k] = h; awsd[r][t][1][k] = m;
            }
            #pragma unroll
            for (int k = 0; k < 4; ++k)
                bias[r][t][k] = be[ir * CC + 16 * t + quad * 4 + k];
        }
    }

    const int q0  = blockIdx.x * PX;
    const int b   = q0 / HWSZ;
    const int hw0 = q0 - b * HWSZ;

    // ---- stage: 2 channels x 2 pixels per thread ----
    #pragma unroll
    for (int kk = 0; kk < 4; ++kk) {
        int idx = tid + kk * 256;            // 1024 = 8n * 16c2 * 8p2
        int p2 = (idx & 7) * 2;
        int c2 = ((idx >> 3) & 15) * 2;
        int n  = idx >> 7;
        const float* gp = nodes + (size_t)((n * BB + b) * CC + c2) * HWSZ + hw0 + p2;
        f32x2 v0 = *(const f32x2*)gp;            // channel c2
        f32x2 v1 = *(const f32x2*)(gp + HWSZ);   // channel c2+1
        #pragma unroll
        for (int e = 0; e < 2; ++e) {
            _Float16 h0, m0, h1, m1;
            split2s(v0[e], h0, m0);
            split2s(v1[e], h1, m1);
            *(f16x2*)&xs[0][n][p2 + e][c2] = f16x2{h0, h1};
            *(f16x2*)&xs[1][n][p2 + e][c2] = f16x2{m0, m1};
            *(f32x2*)&xg[n][p2 + e][c2] = f32x2{v0[e], v1[e]};
        }
    }
    __syncthreads();

    f32x4 msg[2][2];

    #pragma unroll 1
    for (int step = 0; step < NSTEPS; ++step) {
        // ---- Q = (Ws-Wd)_i @ x_i + b : all 4 split products ----
        f32x4 qf[2][2];
        #pragma unroll
        for (int r = 0; r < 2; ++r) {
            const int ir = wid + 4 * r;
            f16x8 bh = *(const f16x8*)&xs[0][ir][col][quad * 8];
            f16x8 bm = *(const f16x8*)&xs[1][ir][col][quad * 8];
            #pragma unroll
            for (int t = 0; t < 2; ++t) {
                f32x4 q1 = MFMA(awsd[r][t][0], bh, bias[r][t]);   // hh (+bias)
                f32x4 q2 = MFMA(awsd[r][t][0], bm, zero4);        // hm
                q2 = MFMA(awsd[r][t][1], bh, q2);                 // mh
                f32x4 q3 = MFMA(awsd[r][t][1], bm, zero4);        // mm
                #pragma unroll
                for (int k = 0; k < 4; ++k)
                    qf[r][t][k] = fmaf(fmaf(q3[k], SINV, q2[k]), SINV, q1[k]);
            }
        }

        #pragma unroll
        for (int r = 0; r < 2; ++r)
            #pragma unroll
            for (int t = 0; t < 2; ++t)
                msg[r][t] = zero4;

        // ---- sender loop: E = Wd x_j + Q (hh, hm, mh kept) ----
        #pragma unroll
        for (int j = 0; j < NN; ++j) {
            f16x8 bh = *(const f16x8*)&xs[0][j][col][quad * 8];
            f16x8 bm = *(const f16x8*)&xs[1][j][col][quad * 8];
            f32x4 xgj[2];
            #pragma unroll
            for (int t = 0; t < 2; ++t)
                xgj[t] = *(const f32x4*)&xg[j][col][16 * t + quad * 4];
            #pragma unroll
            for (int r = 0; r < 2; ++r) {
                if (j == wid + 4 * r) {          // wave-uniform: residual
                    #pragma unroll
                    for (int t = 0; t < 2; ++t)
                        #pragma unroll
                        for (int k = 0; k < 4; ++k)
                            msg[r][t][k] += xgj[t][k];
                } else {
                    #pragma unroll
                    for (int t = 0; t < 2; ++t) {
                        f32x4 e1 = MFMA(awd[r][t][0], bh, qf[r][t]);   // hh (+Q)
                        f32x4 e2 = MFMA(awd[r][t][0], bm, zero4);      // hm
                        e2 = MFMA(awd[r][t][1], bh, e2);               // mh
                        #pragma unroll
                        for (int k = 0; k < 4; ++k) {
                            float g = fmaxf(fmaf(e2[k], SINV, e1[k]), 0.f);
                            msg[r][t][k] = fmaf(g, xgj[t][k], msg[r][t][k]);
                        }
                    }
                }
            }
        }

        if (step < NSTEPS - 1) {
            __syncthreads();   // all reads of old x done
            #pragma unroll
            for (int r = 0; r < 2; ++r) {
                const int ir = wid + 4 * r;
                #pragma unroll
                for (int t = 0; t < 2; ++t) {
                    f16x4 h4, m4;
                    #pragma unroll
                    for (int k = 0; k < 4; ++k) {
                        _Float16 h, m;
                        split2s(msg[r][t][k], h, m);
                        h4[k] = h; m4[k] = m;
                    }
                    *(f16x4*)&xs[0][ir][col][16 * t + quad * 4] = h4;
                    *(f16x4*)&xs[1][ir][col][16 * t + quad * 4] = m4;
                    *(f32x4*)&xg[ir][col][16 * t + quad * 4] = msg[r][t];
                }
            }
            __syncthreads();   // new x visible
        }
    }

    // ---- epilogue: stage final msg in LDS, then full-line coalesced stores ----
    __syncthreads();
    #pragma unroll
    for (int r = 0; r < 2; ++r) {
        const int ir = wid + 4 * r;
        #pragma unroll
        for (int t = 0; t < 2; ++t)
            *(f32x4*)&xg[ir][col][16 * t + quad * 4] = msg[r][t];
    }
    __syncthreads();
    #pragma unroll
    for (int kk = 0; kk < 4; ++kk) {
        int idx = tid + kk * 256;            // 1024 = 8n * 32c * 4p4
        int p4 = (idx & 3) * 4;
        int c  = (idx >> 2) & 31;
        int n  = idx >> 7;
        f32x4 v;
        #pragma unroll
        for (int e = 0; e < 4; ++e) v[e] = xg[n][p4 + e][c];
        *(f32x4*)(out + (size_t)((n * BB + b) * CC + c) * HWSZ + hw0 + p4) = v;
    }
}

extern "C" void kernel_launch(void* const* d_in, const int* in_sizes, int n_in,
                              void* d_out, int out_size, void* d_ws, size_t ws_size,
                              hipStream_t stream) {
    const float* nodes  = (const float*)d_in[0];
    const float* W_edge = (const float*)d_in[1];
    const float* b_edge = (const float*)d_in[2];
    float* outp = (float*)d_out;

    dim3 grid((BB * HWSZ) / PX);   // 2304
    dim3 block(256);
    gcn3_f16<<<grid, block, 0, stream>>>(nodes, W_edge, b_edge, outp);
}

// Round 7
// 136.415 us; speedup vs baseline: 3.1005x; 2.4546x over previous
//
#include <hip/hip_runtime.h>
#include <hip/hip_bf16.h>

// out[i] = sum_{j!=i} relu(Wd_i@x_j + (Ws_i-Wd_i)@x_i + b_i) * x_j + x_i, 3 steps.
// MFMA 16x16x32 f16 with SCALED 2-WAY f16 split: v = h + m*2^-11,
//   h = f16(v), m = f16((v-h)*2048)  -> rep err ~2^-24 (fp32-class; absmax 1.0
//   == fp32 baseline). Edge: keep hh, hm, mh (e = e1 + 2^-11*e2); Q keeps mm too.
// Resident weight frags awd+awsd (64 VGPR) + bias (16).
// __launch_bounds__(256,2): at (256,3) the 84-arch-VGPR cap spilled the hot
// loop (FETCH/WRITE blew up to 272/308 MB scratch traffic, R4/R6). 112 regs
// at 2 blocks/CU is spill-free (proven R2).
// LDS: f16 split pair xs[2] (B-frags) + fp32 gating master xg. Epilogue staged
// through LDS for full-line coalesced stores (R3 direct stores: 2.3x write amp).

#define NN 8
#define NSTEPS 3
#define BB 4
#define CC 32
#define HWSZ 9216
#define PX 16
#define CPS 40   // f16 row stride (80 B)
#define CPG 36   // f32 row stride (144 B)
#define MSC 2048.0f
#define SINV 4.8828125e-4f   // 2^-11

typedef _Float16 f16x8 __attribute__((ext_vector_type(8)));
typedef _Float16 f16x4 __attribute__((ext_vector_type(4)));
typedef _Float16 f16x2 __attribute__((ext_vector_type(2)));
typedef float    f32x4 __attribute__((ext_vector_type(4)));
typedef float    f32x2 __attribute__((ext_vector_type(2)));

#define MFMA(A, B, C) __builtin_amdgcn_mfma_f32_16x16x32_f16((A), (B), (C), 0, 0, 0)

__device__ __forceinline__ void split2s(float v, _Float16& h, _Float16& m) {
    h = (_Float16)v;
    m = (_Float16)((v - (float)h) * MSC);
}

__global__ __launch_bounds__(256, 2)
void gcn3_f16(const float* __restrict__ nodes,
              const float* __restrict__ we,
              const float* __restrict__ be,
              float* __restrict__ out) {
    __shared__ _Float16 xs[2][NN][PX][CPS];   // 20480 B
    __shared__ float    xg[NN][PX][CPG];      // 18432 B (total 38912)

    const int tid  = threadIdx.x;
    const int wid  = tid >> 6;
    const int lane = tid & 63;
    const int col  = lane & 15;    // pixel (B n / C col); A row m
    const int quad = lane >> 4;    // 0..3

    const f32x4 zero4 = {0.f, 0.f, 0.f, 0.f};

    // ---- resident A-frags: Wd and (Ws-Wd), scaled 2-way f16 split ----
    f16x8 awd[2][2][2], awsd[2][2][2];   // [rec][tile][split] = 64 VGPRs
    f32x4 bias[2][2];
    #pragma unroll
    for (int r = 0; r < 2; ++r) {
        const int ir = wid + 4 * r;
        #pragma unroll
        for (int t = 0; t < 2; ++t) {
            const float* wp = we + (size_t)((ir * CC + 16 * t + col) * (2 * CC)) + quad * 8;
            f32x4 d0 = *(const f32x4*)wp;
            f32x4 d1 = *(const f32x4*)(wp + 4);
            f32x4 s0 = *(const f32x4*)(wp + CC);
            f32x4 s1 = *(const f32x4*)(wp + CC + 4);
            #pragma unroll
            for (int k = 0; k < 8; ++k) {
                float d = (k < 4) ? d0[k & 3] : d1[k & 3];
                float s = (k < 4) ? s0[k & 3] : s1[k & 3];
                _Float16 h, m;
                split2s(d, h, m);
                awd[r][t][0][k] = h; awd[r][t][1][k] = m;
                split2s(s - d, h, m);
                awsd[r][t][0][k] = h; awsd[r][t][1][k] = m;
            }
            #pragma unroll
            for (int k = 0; k < 4; ++k)
                bias[r][t][k] = be[ir * CC + 16 * t + quad * 4 + k];
        }
    }

    const int q0  = blockIdx.x * PX;
    const int b   = q0 / HWSZ;
    const int hw0 = q0 - b * HWSZ;

    // ---- stage: 2 channels x 2 pixels per thread ----
    #pragma unroll
    for (int kk = 0; kk < 4; ++kk) {
        int idx = tid + kk * 256;            // 1024 = 8n * 16c2 * 8p2
        int p2 = (idx & 7) * 2;
        int c2 = ((idx >> 3) & 15) * 2;
        int n  = idx >> 7;
        const float* gp = nodes + (size_t)((n * BB + b) * CC + c2) * HWSZ + hw0 + p2;
        f32x2 v0 = *(const f32x2*)gp;            // channel c2
        f32x2 v1 = *(const f32x2*)(gp + HWSZ);   // channel c2+1
        #pragma unroll
        for (int e = 0; e < 2; ++e) {
            _Float16 h0, m0, h1, m1;
            split2s(v0[e], h0, m0);
            split2s(v1[e], h1, m1);
            *(f16x2*)&xs[0][n][p2 + e][c2] = f16x2{h0, h1};
            *(f16x2*)&xs[1][n][p2 + e][c2] = f16x2{m0, m1};
            *(f32x2*)&xg[n][p2 + e][c2] = f32x2{v0[e], v1[e]};
        }
    }
    __syncthreads();

    f32x4 msg[2][2];

    #pragma unroll 1
    for (int step = 0; step < NSTEPS; ++step) {
        // ---- Q = (Ws-Wd)_i @ x_i + b : all 4 split products ----
        f32x4 qf[2][2];
        #pragma unroll
        for (int r = 0; r < 2; ++r) {
            const int ir = wid + 4 * r;
            f16x8 bh = *(const f16x8*)&xs[0][ir][col][quad * 8];
            f16x8 bm = *(const f16x8*)&xs[1][ir][col][quad * 8];
            #pragma unroll
            for (int t = 0; t < 2; ++t) {
                f32x4 q1 = MFMA(awsd[r][t][0], bh, bias[r][t]);   // hh (+bias)
                f32x4 q2 = MFMA(awsd[r][t][0], bm, zero4);        // hm
                q2 = MFMA(awsd[r][t][1], bh, q2);                 // mh
                f32x4 q3 = MFMA(awsd[r][t][1], bm, zero4);        // mm
                #pragma unroll
                for (int k = 0; k < 4; ++k)
                    qf[r][t][k] = fmaf(fmaf(q3[k], SINV, q2[k]), SINV, q1[k]);
            }
        }

        #pragma unroll
        for (int r = 0; r < 2; ++r)
            #pragma unroll
            for (int t = 0; t < 2; ++t)
                msg[r][t] = zero4;

        // ---- sender loop: E = Wd x_j + Q (hh, hm, mh kept) ----
        #pragma unroll
        for (int j = 0; j < NN; ++j) {
            f16x8 bh = *(const f16x8*)&xs[0][j][col][quad * 8];
            f16x8 bm = *(const f16x8*)&xs[1][j][col][quad * 8];
            f32x4 xgj[2];
            #pragma unroll
            for (int t = 0; t < 2; ++t)
                xgj[t] = *(const f32x4*)&xg[j][col][16 * t + quad * 4];
            #pragma unroll
            for (int r = 0; r < 2; ++r) {
                if (j == wid + 4 * r) {          // wave-uniform: residual
                    #pragma unroll
                    for (int t = 0; t < 2; ++t)
                        #pragma unroll
                        for (int k = 0; k < 4; ++k)
                            msg[r][t][k] += xgj[t][k];
                } else {
                    #pragma unroll
                    for (int t = 0; t < 2; ++t) {
                        f32x4 e1 = MFMA(awd[r][t][0], bh, qf[r][t]);   // hh (+Q)
                        f32x4 e2 = MFMA(awd[r][t][0], bm, zero4);      // hm
                        e2 = MFMA(awd[r][t][1], bh, e2);               // mh
                        #pragma unroll
                        for (int k = 0; k < 4; ++k) {
                            float g = fmaxf(fmaf(e2[k], SINV, e1[k]), 0.f);
                            msg[r][t][k] = fmaf(g, xgj[t][k], msg[r][t][k]);
                        }
                    }
                }
            }
        }

        if (step < NSTEPS - 1) {
            __syncthreads();   // all reads of old x done
            #pragma unroll
            for (int r = 0; r < 2; ++r) {
                const int ir = wid + 4 * r;
                #pragma unroll
                for (int t = 0; t < 2; ++t) {
                    f16x4 h4, m4;
                    #pragma unroll
                    for (int k = 0; k < 4; ++k) {
                        _Float16 h, m;
                        split2s(msg[r][t][k], h, m);
                        h4[k] = h; m4[k] = m;
                    }
                    *(f16x4*)&xs[0][ir][col][16 * t + quad * 4] = h4;
                    *(f16x4*)&xs[1][ir][col][16 * t + quad * 4] = m4;
                    *(f32x4*)&xg[ir][col][16 * t + quad * 4] = msg[r][t];
                }
            }
            __syncthreads();   // new x visible
        }
    }

    // ---- epilogue: stage final msg in LDS, then full-line coalesced stores ----
    __syncthreads();
    #pragma unroll
    for (int r = 0; r < 2; ++r) {
        const int ir = wid + 4 * r;
        #pragma unroll
        for (int t = 0; t < 2; ++t)
            *(f32x4*)&xg[ir][col][16 * t + quad * 4] = msg[r][t];
    }
    __syncthreads();
    #pragma unroll
    for (int kk = 0; kk < 4; ++kk) {
        int idx = tid + kk * 256;            // 1024 = 8n * 32c * 4p4
        int p4 = (idx & 3) * 4;
        int c  = (idx >> 2) & 31;
        int n  = idx >> 7;
        f32x4 v;
        #pragma unroll
        for (int e = 0; e < 4; ++e) v[e] = xg[n][p4 + e][c];
        *(f32x4*)(out + (size_t)((n * BB + b) * CC + c) * HWSZ + hw0 + p4) = v;
    }
}

extern "C" void kernel_launch(void* const* d_in, const int* in_sizes, int n_in,
                              void* d_out, int out_size, void* d_ws, size_t ws_size,
                              hipStream_t stream) {
    const float* nodes  = (const float*)d_in[0];
    const float* W_edge = (const float*)d_in[1];
    const float* b_edge = (const float*)d_in[2];
    float* outp = (float*)d_out;

    dim3 grid((BB * HWSZ) / PX);   // 2304
    dim3 block(256);
    gcn3_f16<<<grid, block, 0, stream>>>(nodes, W_edge, b_edge, outp);
}

// Round 8
// 131.908 us; speedup vs baseline: 3.2064x; 1.0342x over previous
//
#include <hip/hip_runtime.h>
#include <hip/hip_bf16.h>

// out[i] = sum_{j!=i} relu(Wd_i@x_j + (Ws_i-Wd_i)@x_i + b_i) * x_j + x_i, 3 steps.
// MFMA 16x16x32 f16 with SCALED 2-WAY f16 split: v = h + m*2^-11 (rep err
// ~2^-24, fp32-class: absmax 1.0 == fp32 baseline R1/R7).
// Edge: hh + 2^-11*(hm+mh); Q keeps mm too.
// R8: 512-thread blocks, 8 waves, wave w = receiver w (ONE receiver/wave).
// Halves per-wave registers (weights 32, qf/msg 16) -> fits the 128-reg cap of
// __launch_bounds__(512,4): 4 waves/SIMD (2 blocks/CU), up from 2 (R7 was
// latency-bound: VALU 38%, MFMA 25%, no pipe saturated).
// Spill go/no-go: FETCH/WRITE must stay ~37/37 MB (R4/R6 spills showed 270+).
// LDS: f16 split pair xs[2] (B-frags) + fp32 gating master xg; staged epilogue.

#define NN 8
#define NSTEPS 3
#define BB 4
#define CC 32
#define HWSZ 9216
#define PX 16
#define CPS 40   // f16 row stride (80 B)
#define CPG 36   // f32 row stride (144 B)
#define MSC 2048.0f
#define SINV 4.8828125e-4f   // 2^-11

typedef _Float16 f16x8 __attribute__((ext_vector_type(8)));
typedef _Float16 f16x4 __attribute__((ext_vector_type(4)));
typedef _Float16 f16x2 __attribute__((ext_vector_type(2)));
typedef float    f32x4 __attribute__((ext_vector_type(4)));
typedef float    f32x2 __attribute__((ext_vector_type(2)));

#define MFMA(A, B, C) __builtin_amdgcn_mfma_f32_16x16x32_f16((A), (B), (C), 0, 0, 0)

__device__ __forceinline__ void split2s(float v, _Float16& h, _Float16& m) {
    h = (_Float16)v;
    m = (_Float16)((v - (float)h) * MSC);
}

__global__ __launch_bounds__(512, 4)
void gcn3_f16w(const float* __restrict__ nodes,
               const float* __restrict__ we,
               const float* __restrict__ be,
               float* __restrict__ out) {
    __shared__ _Float16 xs[2][NN][PX][CPS];   // 20480 B
    __shared__ float    xg[NN][PX][CPG];      // 18432 B (total 38912)

    const int tid  = threadIdx.x;
    const int wid  = tid >> 6;     // receiver node i (0..7), one per wave
    const int lane = tid & 63;
    const int col  = lane & 15;    // pixel (B n / C col); A row m
    const int quad = lane >> 4;    // 0..3

    const f32x4 zero4 = {0.f, 0.f, 0.f, 0.f};

    // ---- resident A-frags for ONE receiver: Wd, (Ws-Wd); 2-way scaled split ----
    f16x8 awd[2][2], awsd[2][2];   // [tile][split] = 32 VGPRs
    f32x4 bias[2];
    #pragma unroll
    for (int t = 0; t < 2; ++t) {
        const float* wp = we + (size_t)((wid * CC + 16 * t + col) * (2 * CC)) + quad * 8;
        f32x4 d0 = *(const f32x4*)wp;
        f32x4 d1 = *(const f32x4*)(wp + 4);
        f32x4 s0 = *(const f32x4*)(wp + CC);
        f32x4 s1 = *(const f32x4*)(wp + CC + 4);
        #pragma unroll
        for (int k = 0; k < 8; ++k) {
            float d = (k < 4) ? d0[k & 3] : d1[k & 3];
            float s = (k < 4) ? s0[k & 3] : s1[k & 3];
            _Float16 h, m;
            split2s(d, h, m);
            awd[t][0][k] = h; awd[t][1][k] = m;
            split2s(s - d, h, m);
            awsd[t][0][k] = h; awsd[t][1][k] = m;
        }
        #pragma unroll
        for (int k = 0; k < 4; ++k)
            bias[t][k] = be[wid * CC + 16 * t + quad * 4 + k];
    }

    const int q0  = blockIdx.x * PX;
    const int b   = q0 / HWSZ;
    const int hw0 = q0 - b * HWSZ;

    // ---- stage: 1024 f32x2 units over 512 threads (2 iters) ----
    #pragma unroll
    for (int kk = 0; kk < 2; ++kk) {
        int idx = tid + kk * 512;            // 1024 = 8n * 16c2 * 8p2
        int p2 = (idx & 7) * 2;
        int c2 = ((idx >> 3) & 15) * 2;
        int n  = idx >> 7;
        const float* gp = nodes + (size_t)((n * BB + b) * CC + c2) * HWSZ + hw0 + p2;
        f32x2 v0 = *(const f32x2*)gp;            // channel c2
        f32x2 v1 = *(const f32x2*)(gp + HWSZ);   // channel c2+1
        #pragma unroll
        for (int e = 0; e < 2; ++e) {
            _Float16 h0, m0, h1, m1;
            split2s(v0[e], h0, m0);
            split2s(v1[e], h1, m1);
            *(f16x2*)&xs[0][n][p2 + e][c2] = f16x2{h0, h1};
            *(f16x2*)&xs[1][n][p2 + e][c2] = f16x2{m0, m1};
            *(f32x2*)&xg[n][p2 + e][c2] = f32x2{v0[e], v1[e]};
        }
    }
    __syncthreads();

    f32x4 msg[2];

    #pragma unroll 1
    for (int step = 0; step < NSTEPS; ++step) {
        // ---- Q = (Ws-Wd)_i @ x_i + b : all 4 split products ----
        f32x4 qf[2];
        {
            f16x8 bh = *(const f16x8*)&xs[0][wid][col][quad * 8];
            f16x8 bm = *(const f16x8*)&xs[1][wid][col][quad * 8];
            #pragma unroll
            for (int t = 0; t < 2; ++t) {
                f32x4 q1 = MFMA(awsd[t][0], bh, bias[t]);   // hh (+bias)
                f32x4 q2 = MFMA(awsd[t][0], bm, zero4);     // hm
                q2 = MFMA(awsd[t][1], bh, q2);              // mh
                f32x4 q3 = MFMA(awsd[t][1], bm, zero4);     // mm
                #pragma unroll
                for (int k = 0; k < 4; ++k)
                    qf[t][k] = fmaf(fmaf(q3[k], SINV, q2[k]), SINV, q1[k]);
            }
        }

        #pragma unroll
        for (int t = 0; t < 2; ++t)
            msg[t] = zero4;

        // ---- sender loop: E = Wd x_j + Q (hh, hm, mh kept) ----
        #pragma unroll
        for (int j = 0; j < NN; ++j) {
            f32x4 xgj[2];
            #pragma unroll
            for (int t = 0; t < 2; ++t)
                xgj[t] = *(const f32x4*)&xg[j][col][16 * t + quad * 4];
            if (j == wid) {                  // wave-uniform: residual
                #pragma unroll
                for (int t = 0; t < 2; ++t)
                    #pragma unroll
                    for (int k = 0; k < 4; ++k)
                        msg[t][k] += xgj[t][k];
            } else {
                f16x8 bh = *(const f16x8*)&xs[0][j][col][quad * 8];
                f16x8 bm = *(const f16x8*)&xs[1][j][col][quad * 8];
                #pragma unroll
                for (int t = 0; t < 2; ++t) {
                    f32x4 e1 = MFMA(awd[t][0], bh, qf[t]);   // hh (+Q)
                    f32x4 e2 = MFMA(awd[t][0], bm, zero4);   // hm
                    e2 = MFMA(awd[t][1], bh, e2);            // mh
                    #pragma unroll
                    for (int k = 0; k < 4; ++k) {
                        float g = fmaxf(fmaf(e2[k], SINV, e1[k]), 0.f);
                        msg[t][k] = fmaf(g, xgj[t][k], msg[t][k]);
                    }
                }
            }
        }

        if (step < NSTEPS - 1) {
            __syncthreads();   // all reads of old x done
            #pragma unroll
            for (int t = 0; t < 2; ++t) {
                f16x4 h4, m4;
                #pragma unroll
                for (int k = 0; k < 4; ++k) {
                    _Float16 h, m;
                    split2s(msg[t][k], h, m);
                    h4[k] = h; m4[k] = m;
                }
                *(f16x4*)&xs[0][wid][col][16 * t + quad * 4] = h4;
                *(f16x4*)&xs[1][wid][col][16 * t + quad * 4] = m4;
                *(f32x4*)&xg[wid][col][16 * t + quad * 4] = msg[t];
            }
            __syncthreads();   // new x visible
        }
    }

    // ---- epilogue: stage final msg in LDS, then full-line coalesced stores ----
    __syncthreads();
    #pragma unroll
    for (int t = 0; t < 2; ++t)
        *(f32x4*)&xg[wid][col][16 * t + quad * 4] = msg[t];
    __syncthreads();
    #pragma unroll
    for (int kk = 0; kk < 2; ++kk) {
        int idx = tid + kk * 512;            // 1024 = 8n * 32c * 4p4
        int p4 = (idx & 3) * 4;
        int c  = (idx >> 2) & 31;
        int n  = idx >> 7;
        f32x4 v;
        #pragma unroll
        for (int e = 0; e < 4; ++e) v[e] = xg[n][p4 + e][c];
        *(f32x4*)(out + (size_t)((n * BB + b) * CC + c) * HWSZ + hw0 + p4) = v;
    }
}

extern "C" void kernel_launch(void* const* d_in, const int* in_sizes, int n_in,
                              void* d_out, int out_size, void* d_ws, size_t ws_size,
                              hipStream_t stream) {
    const float* nodes  = (const float*)d_in[0];
    const float* W_edge = (const float*)d_in[1];
    const float* b_edge = (const float*)d_in[2];
    float* outp = (float*)d_out;

    dim3 grid((BB * HWSZ) / PX);   // 2304 blocks of 512
    dim3 block(512);
    gcn3_f16w<<<grid, block, 0, stream>>>(nodes, W_edge, b_edge, outp);
}